// Round 1
// baseline (11.519 us; speedup 1.0000x reference)
//
#include <hip/hip_runtime.h>

#define N_IMG 16
#define M_PPL 30
#define K_JNT 17
#define S_DIM 16
#define HW (256 * 256)
#define IMG_STRIDE (K_JNT * HW)   // floats per image in tags

// Per-image kernel: computes pull_img, push_img, scale_img for image n = blockIdx.x
__global__ __launch_bounds__(512) void ae_per_image(
    const float* __restrict__ tags,
    const int* __restrict__ joints,       // [N,M,K,2] int32 (loc, vis)
    const float* __restrict__ box_scales, // [N,M]
    const float* __restrict__ scale_dist, // [S]
    float* __restrict__ ws)               // [N,3] per-image results
{
    const int n = blockIdx.x;
    const int t = threadIdx.x;

    __shared__ float g_sh[M_PPL][K_JNT][S_DIM];  // gathered tags (32 KB)
    __shared__ float mean_sh[M_PPL][S_DIM];
    __shared__ int   loc_sh[M_PPL][K_JNT];
    __shared__ float vis_sh[M_PPL][K_JNT];
    __shared__ float cnt_sh[M_PPL];
    __shared__ float pull_sh[M_PPL];
    __shared__ float dsc_sh[M_PPL];
    __shared__ float sd_sh[S_DIM];
    __shared__ float red_sh[8];

    // Phase A: stage joints + scale_dist into LDS
    if (t < S_DIM) sd_sh[t] = scale_dist[t];
    if (t < M_PPL * K_JNT) {
        int m = t / K_JNT, k = t % K_JNT;
        const int* jp = joints + (((long)n * M_PPL + m) * K_JNT + k) * 2;
        loc_sh[m][k] = jp[0];
        vis_sh[m][k] = (jp[1] > 0) ? 1.0f : 0.0f;
    }
    __syncthreads();

    // Phase B: gather + per-person mean. thread t -> (m = t/16, s = t%16)
    const int m = t >> 4;
    const int s = t & 15;
    float meanv = 0.0f;
    float cnt = 0.0f;
    if (m < M_PPL) {
        const float* tbase = tags + (size_t)n * IMG_STRIDE + s;
        float sum = 0.0f;
        #pragma unroll
        for (int k = 0; k < K_JNT; ++k) {
            float v = vis_sh[m][k];
            float g = tbase[(size_t)loc_sh[m][k] * S_DIM];
            g_sh[m][k][s] = g;
            sum += v * g;
            cnt += v;
        }
        meanv = sum / fmaxf(cnt, 1.0f);
        mean_sh[m][s] = meanv;
        if (s == 0) cnt_sh[m] = cnt;
    }
    __syncthreads();

    // Phase C: pull + scale-cosine per person (16 lanes per person)
    if (m < M_PPL) {
        float p = 0.0f;
        #pragma unroll
        for (int k = 0; k < K_JNT; ++k) {
            float d = g_sh[m][k][s] - meanv;
            p += vis_sh[m][k] * d * d;
        }
        float bs  = box_scales[n * M_PPL + m];
        float tgt = 1.0f / (fabsf(bs - sd_sh[s]) + 1e-10f);
        float am  = fabsf(meanv);
        float pr2 = am * am;
        float tg2 = tgt * tgt;
        float dt  = am * tgt;
        #pragma unroll
        for (int o = 1; o < 16; o <<= 1) {
            p   += __shfl_xor(p, o);
            pr2 += __shfl_xor(pr2, o);
            tg2 += __shfl_xor(tg2, o);
            dt  += __shfl_xor(dt, o);
        }
        if (s == 0) {
            pull_sh[m] = p / (fmaxf(cnt, 1.0f) * (float)S_DIM);
            float normP = fmaxf(sqrtf(pr2), 1e-12f);
            float normT = fmaxf(sqrtf(tg2), 1e-12f);
            dsc_sh[m] = 1.0f - dt / (normP * normT);
        }
    }
    __syncthreads();

    // Phase D: push over all ordered pairs (a,b), a != b, both valid
    float psum = 0.0f;
    for (int p = t; p < M_PPL * M_PPL; p += 512) {
        int a = p / M_PPL, b = p - a * M_PPL;
        if (a != b && cnt_sh[a] > 0.0f && cnt_sh[b] > 0.0f) {
            float d2 = 0.0f;
            #pragma unroll
            for (int ss = 0; ss < S_DIM; ++ss) {
                float d = mean_sh[a][ss] - mean_sh[b][ss];
                d2 += d * d;
            }
            psum += expf(-d2);
        }
    }
    #pragma unroll
    for (int o = 1; o < 64; o <<= 1) psum += __shfl_xor(psum, o);
    if ((t & 63) == 0) red_sh[t >> 6] = psum;
    __syncthreads();

    // Phase E: per-image reduction, thread 0
    if (t == 0) {
        float push_total = 0.0f;
        #pragma unroll
        for (int w = 0; w < 8; ++w) push_total += red_sh[w];
        float nval = 0.0f, pullsum = 0.0f, scsum = 0.0f;
        for (int mm = 0; mm < M_PPL; ++mm) {
            if (cnt_sh[mm] > 0.0f) {
                nval += 1.0f;
                pullsum += pull_sh[mm];
                scsum   += dsc_sh[mm];
            }
        }
        float safe_n = fmaxf(nval, 1.0f);
        float push_img = (nval >= 2.0f)
                           ? 0.5f * push_total / fmaxf(nval * (nval - 1.0f), 1.0f)
                           : 0.0f;
        ws[n * 3 + 0] = pullsum / safe_n;
        ws[n * 3 + 1] = push_img;
        ws[n * 3 + 2] = scsum / safe_n;
    }
}

// Final reduction over N images -> 3 scalars
__global__ void ae_finalize(const float* __restrict__ ws, float* __restrict__ out)
{
    int t = threadIdx.x;
    if (t < 3) {
        float sacc = 0.0f;
        #pragma unroll
        for (int n = 0; n < N_IMG; ++n) sacc += ws[n * 3 + t];
        out[t] = sacc / (float)N_IMG;
    }
}

extern "C" void kernel_launch(void* const* d_in, const int* in_sizes, int n_in,
                              void* d_out, int out_size, void* d_ws, size_t ws_size,
                              hipStream_t stream) {
    const float* tags       = (const float*)d_in[0];
    const int*   joints     = (const int*)d_in[1];
    const float* box_scales = (const float*)d_in[2];
    const float* scale_dist = (const float*)d_in[3];
    float* out = (float*)d_out;
    float* ws  = (float*)d_ws;

    ae_per_image<<<N_IMG, 512, 0, stream>>>(tags, joints, box_scales, scale_dist, ws);
    ae_finalize<<<1, 64, 0, stream>>>(ws, out);
}